// Round 10
// baseline (1191.302 us; speedup 1.0000x reference)
//
#include <hip/hip_runtime.h>
#include <hip/hip_bf16.h>

#define TSEQ   2048
#define DMODEL 768
#define NHEAD  12
#define DHEAD  64
#define NLAYER 4
#define VOCAB  50257
#define VPAD   50304   // VOCAB rounded up to 128

typedef __attribute__((ext_vector_type(8))) short short8;
typedef __attribute__((ext_vector_type(4))) float f32x4;
typedef unsigned short ushort_t;

union F8 { short8 v; unsigned long long q[2]; };

__device__ __forceinline__ float b2f(ushort_t u) {
  return __uint_as_float(((unsigned)u) << 16);
}
__device__ __forceinline__ ushort_t f2bu(float f) {  // RNE f32->bf16
  unsigned u = __float_as_uint(f);
  unsigned r = (u + 0x7fffu + ((u >> 16) & 1u)) >> 16;
  return (ushort_t)r;
}

__device__ __forceinline__ void gload_lds16(const void* g, void* l) {
  __builtin_amdgcn_global_load_lds(
      (const __attribute__((address_space(1))) unsigned int*)g,
      (__attribute__((address_space(3))) unsigned int*)l, 16, 0, 0);
}

// ---------------------------------------------------------------- embedding
__global__ __launch_bounds__(256) void embed_kernel(
    const int* __restrict__ tok, const float* __restrict__ wte,
    const float* __restrict__ wpe, float* __restrict__ x) {
  int i = blockIdx.x * 256 + threadIdx.x;
  int t = i / DMODEL;
  int d = i - t * DMODEL;
  x[i] = wte[tok[t] * DMODEL + d] + wpe[i];
}

// ---------------------------------------------------------------- fp32->bf16 convert
__global__ __launch_bounds__(256) void cvt_kernel(
    const float* __restrict__ in, ushort_t* __restrict__ out, int n4) {
  for (int i = blockIdx.x * 256 + threadIdx.x; i < n4; i += gridDim.x * 256) {
    float4 f = reinterpret_cast<const float4*>(in)[i];
    ushort4 o;
    o.x = f2bu(f.x); o.y = f2bu(f.y); o.z = f2bu(f.z); o.w = f2bu(f.w);
    reinterpret_cast<ushort4*>(out)[i] = o;
  }
}

// ---------------------------------------------------------------- transpose + convert  W[K,N] -> Wt[N,K] bf16
__global__ __launch_bounds__(256) void tcvt_kernel(
    const float* __restrict__ W, ushort_t* __restrict__ Wt, int K, int N,
    long long wstride) {
  W  += (size_t)blockIdx.z * wstride;
  Wt += (size_t)blockIdx.z * wstride;
  __shared__ float Ts[32][33];
  int n0 = blockIdx.x * 32, k0 = blockIdx.y * 32;
  int tx = threadIdx.x & 31, ty = threadIdx.x >> 5;
#pragma unroll
  for (int s = 0; s < 4; ++s)
    Ts[ty + 8 * s][tx] = W[(size_t)(k0 + ty + 8 * s) * N + n0 + tx];
  __syncthreads();
#pragma unroll
  for (int s = 0; s < 4; ++s)
    Wt[(size_t)(n0 + ty + 8 * s) * K + k0 + tx] = f2bu(Ts[tx][ty + 8 * s]);
}

// ---------------------------------------------------------------- layernorm (fp32 in, bf16 out)
__global__ __launch_bounds__(256) void ln_kernel(
    const float* __restrict__ x, const float* __restrict__ w,
    const float* __restrict__ b, ushort_t* __restrict__ out) {
  int row = blockIdx.x;
  int t = threadIdx.x;
  const float* xr = x + row * DMODEL;
  float v0 = xr[t], v1 = xr[t + 256], v2 = xr[t + 512];
  float s = v0 + v1 + v2;
  float q = v0 * v0 + v1 * v1 + v2 * v2;
#pragma unroll
  for (int off = 32; off >= 1; off >>= 1) {
    s += __shfl_xor(s, off);
    q += __shfl_xor(q, off);
  }
  __shared__ float rs[4], rq[4];
  int wid = t >> 6;
  if ((t & 63) == 0) { rs[wid] = s; rq[wid] = q; }
  __syncthreads();
  s = rs[0] + rs[1] + rs[2] + rs[3];
  q = rq[0] + rq[1] + rq[2] + rq[3];
  float mean = s * (1.f / DMODEL);
  float var  = q * (1.f / DMODEL) - mean * mean;
  float rstd = rsqrtf(var + 1e-5f);
  ushort_t* o = out + row * DMODEL;
  o[t]       = f2bu((v0 - mean) * rstd * w[t]       + b[t]);
  o[t + 256] = f2bu((v1 - mean) * rstd * w[t + 256] + b[t + 256]);
  o[t + 512] = f2bu((v2 - mean) * rstd * w[t + 512] + b[t + 512]);
}

// ---------------------------------------------------------------- bf16 MFMA GEMM, BK=64 single-buffer (proven round-4 config)
// NT: nontemporal C store (lm_head only -- keeps wte B-panels hot in L2).
template <int TM, int TN, bool BIAS, bool RES, bool GELU, bool OUTBF16, bool XSWZ, bool NT>
__global__ __launch_bounds__(256) void mm_kernel(
    const ushort_t* __restrict__ A, const ushort_t* __restrict__ Bt,
    const float* __restrict__ bias, const float* __restrict__ res,
    void* __restrict__ outp, int N, int K, int nrowblk, int nwg) {
  constexpr int HM = TM / 2, HN = TN / 2, FI = TM / 32, FJ = TN / 32;
  constexpr int NCA = TM / 32, NCB = TN / 32;
  __shared__ ushort_t Asm[TM * 64];
  __shared__ ushort_t Bsm[TN * 64];
  const int tid = threadIdx.x;
  const int lane = tid & 63, wid = tid >> 6;
  const int wr = wid >> 1, wc = wid & 1;
  const int l15 = lane & 15, c4 = lane >> 4;
  const int qb0 = (c4 >> 1) << 4;
  const int qb1 = qb0 + 32;
  const int e8 = (c4 & 1) * 8;

  int bid = blockIdx.x;
  if (XSWZ) { int q = nwg >> 3; bid = (bid & 7) * q + (bid >> 3); }
  const int rowb = bid % nrowblk, colb = bid / nrowblk;
  const int rowA0 = rowb * TM, colB0 = colb * TN;

  int ap0[FI], ax[FI], bp0[FJ], bx[FJ];
#pragma unroll
  for (int i = 0; i < FI; ++i) {
    int r = wr * HM + i * 16 + l15;
    ap0[i] = r * 128 + e8; ax[i] = (r & 7) << 4;
  }
#pragma unroll
  for (int j = 0; j < FJ; ++j) {
    int r = wc * HN + j * 16 + l15;
    bp0[j] = r * 128 + e8; bx[j] = (r & 7) << 4;
  }

  const ushort_t* asrc[NCA]; ushort_t* adst[NCA];
  const ushort_t* bsrc[NCB]; ushort_t* bdst[NCB];
#pragma unroll
  for (int s = 0; s < NCA; ++s) {
    int ci = tid + s * 256;
    int row = ci >> 3;
    int logch = (ci & 7) ^ (row & 7);
    asrc[s] = A + (size_t)(rowA0 + row) * K + logch * 8;
    adst[s] = Asm + ci * 8;
  }
#pragma unroll
  for (int s = 0; s < NCB; ++s) {
    int ci = tid + s * 256;
    int row = ci >> 3;
    int logch = (ci & 7) ^ (row & 7);
    bsrc[s] = Bt + (size_t)(colB0 + row) * K + logch * 8;
    bdst[s] = Bsm + ci * 8;
  }

  f32x4 acc[FI][FJ] = {};
  const char* Ab = (const char*)Asm;
  const char* Bb = (const char*)Bsm;

  for (int kt = 0; kt < K; kt += 64) {
    __syncthreads();
#pragma unroll
    for (int s = 0; s < NCA; ++s) gload_lds16(asrc[s] + kt, adst[s]);
#pragma unroll
    for (int s = 0; s < NCB; ++s) gload_lds16(bsrc[s] + kt, bdst[s]);
    __syncthreads();
#pragma unroll
    for (int kk = 0; kk < 2; ++kk) {
      const int k64 = kk * 64;
      short8 a[FI], b[FJ];
#pragma unroll
      for (int i = 0; i < FI; ++i) {
        F8 f;
        f.q[0] = *(const unsigned long long*)(Ab + ap0[i] + ((k64 + qb0) ^ ax[i]));
        f.q[1] = *(const unsigned long long*)(Ab + ap0[i] + ((k64 + qb1) ^ ax[i]));
        a[i] = f.v;
      }
#pragma unroll
      for (int j = 0; j < FJ; ++j) {
        F8 f;
        f.q[0] = *(const unsigned long long*)(Bb + bp0[j] + ((k64 + qb0) ^ bx[j]));
        f.q[1] = *(const unsigned long long*)(Bb + bp0[j] + ((k64 + qb1) ^ bx[j]));
        b[j] = f.v;
      }
#pragma unroll
      for (int i = 0; i < FI; ++i)
#pragma unroll
        for (int j = 0; j < FJ; ++j)
          acc[i][j] = __builtin_amdgcn_mfma_f32_16x16x32_bf16(a[i], b[j], acc[i][j], 0, 0, 0);
    }
  }

#pragma unroll
  for (int i = 0; i < FI; ++i) {
    const int rbase = rowA0 + wr * HM + i * 16 + c4 * 4;
#pragma unroll
    for (int j = 0; j < FJ; ++j) {
      const int col = colB0 + wc * HN + j * 16 + l15;
      if (col < N) {
        float bv = BIAS ? bias[col] : 0.f;
#pragma unroll
        for (int t = 0; t < 4; ++t) {
          float v = acc[i][j][t] + bv;
          if (GELU) {
            float z = 1.5957691216057308f * (v + 0.044715f * v * v * v);
            float th = 1.f - 2.f / (__expf(z) + 1.f);
            v = 0.5f * v * (1.f + th);
          }
          size_t o = (size_t)(rbase + t) * N + col;
          if (RES)          ((float*)outp)[o] = v + res[o];
          else if (OUTBF16) ((ushort_t*)outp)[o] = f2bu(v);
          else if (NT)      __builtin_nontemporal_store(v, &((float*)outp)[o]);
          else              ((float*)outp)[o] = v;
        }
      }
    }
  }
}

// ---------------------------------------------------------------- MFMA flash attention
__global__ __launch_bounds__(256) void fattn_kernel(
    const ushort_t* __restrict__ qkv, ushort_t* __restrict__ y) {
  const int id = blockIdx.x;
  const int w32 = id / NHEAD;
  const int h = id - w32 * NHEAD;
  const int qb = (w32 & 1) ? (w32 >> 1) : (31 - (w32 >> 1));
  const int q0 = qb * 64;

  __shared__ ushort_t Ksm[64 * 64];
  __shared__ ushort_t Vsm[64 * 64];
  __shared__ ushort_t Psm[4 * 16 * 64];

  const int tid = threadIdx.x;
  const int lane = tid & 63, wv = tid >> 6;
  const int l15 = lane & 15, c4 = lane >> 4;
  const int r7 = l15 & 7;

  const ushort_t* qrow = qkv + (size_t)(q0 + wv * 16 + l15) * (3 * DMODEL) + h * DHEAD;
  const short8 qf0 = *(const short8*)(qrow + c4 * 8);
  const short8 qf1 = *(const short8*)(qrow + 32 + c4 * 8);

  const ushort_t* ksrc[2]; ushort_t* kdst[2];
#pragma unroll
  for (int s = 0; s < 2; ++s) {
    int row = wv * 16 + s * 8 + (lane >> 3);
    int cs = (lane & 7) ^ (row & 7);
    ksrc[s] = qkv + (size_t)row * (3 * DMODEL) + DMODEL + h * DHEAD + cs * 8;
    kdst[s] = Ksm + ((wv * 2 + s) * 64) * 8;
  }
  const int vk = tid & 63, vd0 = (tid >> 6) * 8;
  const ushort_t* vsrc = qkv + (size_t)vk * (3 * DMODEL) + 2 * DMODEL + h * DHEAD;
  const int vkoff = ((vk >> 3) << 3) + (vk & 7);

  float m[4] = {-1e30f, -1e30f, -1e30f, -1e30f};
  float l[4] = {};
  f32x4 acc[4] = {};
  ushort_t* Pw = Psm + wv * 1024;

  for (int k0 = 0; k0 <= q0; k0 += 64) {
    const size_t koff = (size_t)k0 * (3 * DMODEL);
    short8 v0 = *(const short8*)(vsrc + koff + vd0);
    short8 v1 = *(const short8*)(vsrc + koff + vd0 + 32);
    __syncthreads();
#pragma unroll
    for (int s = 0; s < 2; ++s) gload_lds16(ksrc[s] + koff, kdst[s]);
#pragma unroll
    for (int j = 0; j < 8; ++j) {
      int d = vd0 + j;
      Vsm[d * 64 + (vkoff ^ ((d & 7) << 3))] = (ushort_t)v0[j];
      int d2 = d + 32;
      Vsm[d2 * 64 + (vkoff ^ ((d2 & 7) << 3))] = (ushort_t)v1[j];
    }
    __syncthreads();

    f32x4 sv[4];
#pragma unroll
    for (int kt = 0; kt < 4; ++kt) {
      const ushort_t* krow = Ksm + (kt * 16 + l15) * 64;
      short8 kb0 = *(const short8*)(krow + ((c4 ^ r7) << 3));
      short8 kb1 = *(const short8*)(krow + (((4 + c4) ^ r7) << 3));
      f32x4 s = {};
      s = __builtin_amdgcn_mfma_f32_16x16x32_bf16(qf0, kb0, s, 0, 0, 0);
      s = __builtin_amdgcn_mfma_f32_16x16x32_bf16(qf1, kb1, s, 0, 0, 0);
      sv[kt] = s * 0.125f;
    }
    if (k0 == q0) {
#pragma unroll
      for (int kt = 0; kt < 4; ++kt)
#pragma unroll
        for (int r = 0; r < 4; ++r)
          if (kt * 16 + l15 > wv * 16 + c4 * 4 + r) sv[kt][r] = -1e30f;
    }

#pragma unroll
    for (int r = 0; r < 4; ++r) {
      float mv = fmaxf(fmaxf(sv[0][r], sv[1][r]), fmaxf(sv[2][r], sv[3][r]));
      mv = fmaxf(mv, __shfl_xor(mv, 1));
      mv = fmaxf(mv, __shfl_xor(mv, 2));
      mv = fmaxf(mv, __shfl_xor(mv, 4));
      mv = fmaxf(mv, __shfl_xor(mv, 8));
      float nm = fmaxf(m[r], mv);
      float sc = __expf(m[r] - nm);
      m[r] = nm;
      const int row = c4 * 4 + r;
      float sum = 0.f;
#pragma unroll
      for (int kt = 0; kt < 4; ++kt) {
        float p = __expf(sv[kt][r] - nm);
        sum += p;
        Pw[row * 64 + (((kt * 2 + (l15 >> 3)) ^ (row & 7)) << 3) + (l15 & 7)] = f2bu(p);
      }
      sum += __shfl_xor(sum, 1);
      sum += __shfl_xor(sum, 2);
      sum += __shfl_xor(sum, 4);
      sum += __shfl_xor(sum, 8);
      l[r] = l[r] * sc + sum;
#pragma unroll
      for (int j = 0; j < 4; ++j) acc[j][r] *= sc;
    }

    const ushort_t* prow = Pw + l15 * 64;
    short8 pa0 = *(const short8*)(prow + ((c4 ^ r7) << 3));
    short8 pa1 = *(const short8*)(prow + (((4 + c4) ^ r7) << 3));
#pragma unroll
    for (int j = 0; j < 4; ++j) {
      const ushort_t* vrow = Vsm + (j * 16 + l15) * 64;
      short8 vb0 = *(const short8*)(vrow + ((c4 ^ r7) << 3));
      short8 vb1 = *(const short8*)(vrow + (((4 + c4) ^ r7) << 3));
      acc[j] = __builtin_amdgcn_mfma_f32_16x16x32_bf16(pa0, vb0, acc[j], 0, 0, 0);
      acc[j] = __builtin_amdgcn_mfma_f32_16x16x32_bf16(pa1, vb1, acc[j], 0, 0, 0);
    }
  }

  float inv[4];
#pragma unroll
  for (int r = 0; r < 4; ++r) inv[r] = 1.f / l[r];
#pragma unroll
  for (int j = 0; j < 4; ++j)
#pragma unroll
    for (int r = 0; r < 4; ++r)
      y[(size_t)(q0 + wv * 16 + c4 * 4 + r) * DMODEL + h * DHEAD + j * 16 + l15] =
          f2bu(acc[j][r] * inv[r]);
}

// ---------------------------------------------------------------- driver
extern "C" void kernel_launch(void* const* d_in, const int* in_sizes, int n_in,
                              void* d_out, int out_size, void* d_ws, size_t ws_size,
                              hipStream_t stream) {
  const int*   tokens = (const int*)d_in[0];
  const float* wte    = (const float*)d_in[1];
  const float* wpe    = (const float*)d_in[2];
  const float* ln1_w  = (const float*)d_in[3];
  const float* ln1_b  = (const float*)d_in[4];
  const float* qkv_w  = (const float*)d_in[5];
  const float* qkv_b  = (const float*)d_in[6];
  const float* proj_w = (const float*)d_in[7];
  const float* proj_b = (const float*)d_in[8];
  const float* ln2_w  = (const float*)d_in[9];
  const float* ln2_b  = (const float*)d_in[10];
  const float* fc_w   = (const float*)d_in[11];
  const float* fc_b   = (const float*)d_in[12];
  const float* fcp_w  = (const float*)d_in[13];
  const float* fcp_b  = (const float*)d_in[14];
  const float* lnf_w  = (const float*)d_in[15];
  const float* lnf_b  = (const float*)d_in[16];
  float* out = (float*)d_out;

  char* p = (char*)d_ws;
  auto alloc = [&](size_t bytes) { char* r = p; p += (bytes + 255) & ~(size_t)255; return r; };
  float*    x     = (float*)alloc((size_t)TSEQ * DMODEL * 4);
  ushort_t* lnb   = (ushort_t*)alloc((size_t)TSEQ * DMODEL * 2);
  ushort_t* buf   = (ushort_t*)alloc((size_t)TSEQ * 4 * DMODEL * 2); // qkv|y == hfc
  ushort_t* wteb  = (ushort_t*)alloc((size_t)VPAD * DMODEL * 2);
  ushort_t* qkvwt = (ushort_t*)alloc((size_t)NLAYER * 3 * DMODEL * DMODEL * 2);
  ushort_t* projwt= (ushort_t*)alloc((size_t)NLAYER * DMODEL * DMODEL * 2);
  ushort_t* fcwt  = (ushort_t*)alloc((size_t)NLAYER * 4 * DMODEL * DMODEL * 2);
  ushort_t* fcpwt = (ushort_t*)alloc((size_t)NLAYER * 4 * DMODEL * DMODEL * 2);
  ushort_t* qkvb  = buf;
  ushort_t* yb    = buf + (size_t)TSEQ * 3 * DMODEL;
  ushort_t* hfcb  = buf;

  dim3 b256(256);

  // zero the vocab padding rows of wteb (read by B-staging, write-guarded)
  hipMemsetAsync(wteb + (size_t)VOCAB * DMODEL, 0,
                 (size_t)(VPAD - VOCAB) * DMODEL * 2, stream);
  cvt_kernel<<<dim3(4096), b256, 0, stream>>>(wte, wteb, VOCAB * DMODEL / 4);
  tcvt_kernel<<<dim3(3 * DMODEL / 32, DMODEL / 32, NLAYER), b256, 0, stream>>>(
      qkv_w, qkvwt, DMODEL, 3 * DMODEL, (long long)3 * DMODEL * DMODEL);
  tcvt_kernel<<<dim3(DMODEL / 32, DMODEL / 32, NLAYER), b256, 0, stream>>>(
      proj_w, projwt, DMODEL, DMODEL, (long long)DMODEL * DMODEL);
  tcvt_kernel<<<dim3(4 * DMODEL / 32, DMODEL / 32, NLAYER), b256, 0, stream>>>(
      fc_w, fcwt, DMODEL, 4 * DMODEL, (long long)4 * DMODEL * DMODEL);
  tcvt_kernel<<<dim3(DMODEL / 32, 4 * DMODEL / 32, NLAYER), b256, 0, stream>>>(
      fcp_w, fcpwt, 4 * DMODEL, DMODEL, (long long)4 * DMODEL * DMODEL);

  embed_kernel<<<dim3(TSEQ * DMODEL / 256), b256, 0, stream>>>(tokens, wte, wpe, x);

  for (int l = 0; l < NLAYER; ++l) {
    ln_kernel<<<dim3(TSEQ), b256, 0, stream>>>(x, ln1_w + l * DMODEL, ln1_b + l * DMODEL, lnb);
    // qkv: 64x128 tile -> 576 blocks (2.25/CU co-residency)
    mm_kernel<64, 128, true, false, false, true, false, false><<<dim3(32 * 18), b256, 0, stream>>>(
        lnb, qkvwt + (size_t)l * 3 * DMODEL * DMODEL, qkv_b + (size_t)l * 3 * DMODEL,
        nullptr, qkvb, 3 * DMODEL, DMODEL, 32, 576);
    fattn_kernel<<<dim3(32 * NHEAD), b256, 0, stream>>>(qkvb, yb);
    mm_kernel<64, 64, true, true, false, false, false, false><<<dim3(12 * 32), b256, 0, stream>>>(
        yb, projwt + (size_t)l * DMODEL * DMODEL, proj_b + (size_t)l * DMODEL,
        x, x, DMODEL, DMODEL, 32, 384);
    ln_kernel<<<dim3(TSEQ), b256, 0, stream>>>(x, ln2_w + l * DMODEL, ln2_b + l * DMODEL, lnb);
    // fc: 64x128 tile -> 768 blocks (3/CU)
    mm_kernel<64, 128, true, false, true, true, false, false><<<dim3(32 * 24), b256, 0, stream>>>(
        lnb, fcwt + (size_t)l * 4 * DMODEL * DMODEL, fc_b + (size_t)l * 4 * DMODEL,
        nullptr, hfcb, 4 * DMODEL, DMODEL, 32, 768);
    mm_kernel<64, 64, true, true, false, false, false, false><<<dim3(12 * 32), b256, 0, stream>>>(
        hfcb, fcpwt + (size_t)l * DMODEL * 4 * DMODEL, fcp_b + (size_t)l * DMODEL,
        x, x, DMODEL, 4 * DMODEL, 32, 384);
  }

  ln_kernel<<<dim3(TSEQ), b256, 0, stream>>>(x, lnf_w, lnf_b, lnb);
  mm_kernel<128, 128, false, false, false, false, true, true><<<dim3(393 * 16), b256, 0, stream>>>(
      lnb, wteb, nullptr, nullptr, out, VOCAB, DMODEL, 16, 393 * 16);
}

// Round 11
// 1048.648 us; speedup vs baseline: 1.1360x; 1.1360x over previous
//
#include <hip/hip_runtime.h>
#include <hip/hip_bf16.h>

#define TSEQ   2048
#define DMODEL 768
#define NHEAD  12
#define DHEAD  64
#define NLAYER 4
#define VOCAB  50257
#define VPAD   50304   // VOCAB rounded up to 128

typedef __attribute__((ext_vector_type(8))) short short8;
typedef __attribute__((ext_vector_type(4))) float f32x4;
typedef unsigned short ushort_t;

union F8 { short8 v; unsigned long long q[2]; };

__device__ __forceinline__ float b2f(ushort_t u) {
  return __uint_as_float(((unsigned)u) << 16);
}
__device__ __forceinline__ ushort_t f2bu(float f) {  // RNE f32->bf16
  unsigned u = __float_as_uint(f);
  unsigned r = (u + 0x7fffu + ((u >> 16) & 1u)) >> 16;
  return (ushort_t)r;
}

__device__ __forceinline__ void gload_lds16(const void* g, void* l) {
  __builtin_amdgcn_global_load_lds(
      (const __attribute__((address_space(1))) unsigned int*)g,
      (__attribute__((address_space(3))) unsigned int*)l, 16, 0, 0);
}

// ---------------------------------------------------------------- embedding
__global__ __launch_bounds__(256) void embed_kernel(
    const int* __restrict__ tok, const float* __restrict__ wte,
    const float* __restrict__ wpe, float* __restrict__ x) {
  int i = blockIdx.x * 256 + threadIdx.x;
  int t = i / DMODEL;
  int d = i - t * DMODEL;
  x[i] = wte[tok[t] * DMODEL + d] + wpe[i];
}

// ---------------------------------------------------------------- fp32->bf16 convert
__global__ __launch_bounds__(256) void cvt_kernel(
    const float* __restrict__ in, ushort_t* __restrict__ out, int n4) {
  for (int i = blockIdx.x * 256 + threadIdx.x; i < n4; i += gridDim.x * 256) {
    float4 f = reinterpret_cast<const float4*>(in)[i];
    ushort4 o;
    o.x = f2bu(f.x); o.y = f2bu(f.y); o.z = f2bu(f.z); o.w = f2bu(f.w);
    reinterpret_cast<ushort4*>(out)[i] = o;
  }
}

// ---------------------------------------------------------------- transpose + convert  W[K,N] -> Wt[N,K] bf16
__global__ __launch_bounds__(256) void tcvt_kernel(
    const float* __restrict__ W, ushort_t* __restrict__ Wt, int K, int N,
    long long wstride) {
  W  += (size_t)blockIdx.z * wstride;
  Wt += (size_t)blockIdx.z * wstride;
  __shared__ float Ts[32][33];
  int n0 = blockIdx.x * 32, k0 = blockIdx.y * 32;
  int tx = threadIdx.x & 31, ty = threadIdx.x >> 5;
#pragma unroll
  for (int s = 0; s < 4; ++s)
    Ts[ty + 8 * s][tx] = W[(size_t)(k0 + ty + 8 * s) * N + n0 + tx];
  __syncthreads();
#pragma unroll
  for (int s = 0; s < 4; ++s)
    Wt[(size_t)(n0 + ty + 8 * s) * K + k0 + tx] = f2bu(Ts[tx][ty + 8 * s]);
}

// ---------------------------------------------------------------- layernorm (fp32 in, bf16 out)
__global__ __launch_bounds__(256) void ln_kernel(
    const float* __restrict__ x, const float* __restrict__ w,
    const float* __restrict__ b, ushort_t* __restrict__ out) {
  int row = blockIdx.x;
  int t = threadIdx.x;
  const float* xr = x + row * DMODEL;
  float v0 = xr[t], v1 = xr[t + 256], v2 = xr[t + 512];
  float s = v0 + v1 + v2;
  float q = v0 * v0 + v1 * v1 + v2 * v2;
#pragma unroll
  for (int off = 32; off >= 1; off >>= 1) {
    s += __shfl_xor(s, off);
    q += __shfl_xor(q, off);
  }
  __shared__ float rs[4], rq[4];
  int wid = t >> 6;
  if ((t & 63) == 0) { rs[wid] = s; rq[wid] = q; }
  __syncthreads();
  s = rs[0] + rs[1] + rs[2] + rs[3];
  q = rq[0] + rq[1] + rq[2] + rq[3];
  float mean = s * (1.f / DMODEL);
  float var  = q * (1.f / DMODEL) - mean * mean;
  float rstd = rsqrtf(var + 1e-5f);
  ushort_t* o = out + row * DMODEL;
  o[t]       = f2bu((v0 - mean) * rstd * w[t]       + b[t]);
  o[t + 256] = f2bu((v1 - mean) * rstd * w[t + 256] + b[t + 256]);
  o[t + 512] = f2bu((v2 - mean) * rstd * w[t + 512] + b[t + 512]);
}

// ---------------------------------------------------------------- bf16 MFMA GEMM, BK=64 single-buffer (proven round-4 config)
template <int TM, int TN, bool BIAS, bool RES, bool GELU, bool OUTBF16, bool XSWZ>
__global__ __launch_bounds__(256) void mm_kernel(
    const ushort_t* __restrict__ A, const ushort_t* __restrict__ Bt,
    const float* __restrict__ bias, const float* __restrict__ res,
    void* __restrict__ outp, int N, int K, int nrowblk, int nwg) {
  constexpr int HM = TM / 2, HN = TN / 2, FI = TM / 32, FJ = TN / 32;
  constexpr int NCA = TM / 32, NCB = TN / 32;
  __shared__ ushort_t Asm[TM * 64];
  __shared__ ushort_t Bsm[TN * 64];
  const int tid = threadIdx.x;
  const int lane = tid & 63, wid = tid >> 6;
  const int wr = wid >> 1, wc = wid & 1;
  const int l15 = lane & 15, c4 = lane >> 4;
  const int qb0 = (c4 >> 1) << 4;
  const int qb1 = qb0 + 32;
  const int e8 = (c4 & 1) * 8;

  int bid = blockIdx.x;
  if (XSWZ) { int q = nwg >> 3; bid = (bid & 7) * q + (bid >> 3); }
  const int rowb = bid % nrowblk, colb = bid / nrowblk;
  const int rowA0 = rowb * TM, colB0 = colb * TN;

  int ap0[FI], ax[FI], bp0[FJ], bx[FJ];
#pragma unroll
  for (int i = 0; i < FI; ++i) {
    int r = wr * HM + i * 16 + l15;
    ap0[i] = r * 128 + e8; ax[i] = (r & 7) << 4;
  }
#pragma unroll
  for (int j = 0; j < FJ; ++j) {
    int r = wc * HN + j * 16 + l15;
    bp0[j] = r * 128 + e8; bx[j] = (r & 7) << 4;
  }

  const ushort_t* asrc[NCA]; ushort_t* adst[NCA];
  const ushort_t* bsrc[NCB]; ushort_t* bdst[NCB];
#pragma unroll
  for (int s = 0; s < NCA; ++s) {
    int ci = tid + s * 256;
    int row = ci >> 3;
    int logch = (ci & 7) ^ (row & 7);
    asrc[s] = A + (size_t)(rowA0 + row) * K + logch * 8;
    adst[s] = Asm + ci * 8;
  }
#pragma unroll
  for (int s = 0; s < NCB; ++s) {
    int ci = tid + s * 256;
    int row = ci >> 3;
    int logch = (ci & 7) ^ (row & 7);
    bsrc[s] = Bt + (size_t)(colB0 + row) * K + logch * 8;
    bdst[s] = Bsm + ci * 8;
  }

  f32x4 acc[FI][FJ] = {};
  const char* Ab = (const char*)Asm;
  const char* Bb = (const char*)Bsm;

  for (int kt = 0; kt < K; kt += 64) {
    __syncthreads();
#pragma unroll
    for (int s = 0; s < NCA; ++s) gload_lds16(asrc[s] + kt, adst[s]);
#pragma unroll
    for (int s = 0; s < NCB; ++s) gload_lds16(bsrc[s] + kt, bdst[s]);
    __syncthreads();
#pragma unroll
    for (int kk = 0; kk < 2; ++kk) {
      const int k64 = kk * 64;
      short8 a[FI], b[FJ];
#pragma unroll
      for (int i = 0; i < FI; ++i) {
        F8 f;
        f.q[0] = *(const unsigned long long*)(Ab + ap0[i] + ((k64 + qb0) ^ ax[i]));
        f.q[1] = *(const unsigned long long*)(Ab + ap0[i] + ((k64 + qb1) ^ ax[i]));
        a[i] = f.v;
      }
#pragma unroll
      for (int j = 0; j < FJ; ++j) {
        F8 f;
        f.q[0] = *(const unsigned long long*)(Bb + bp0[j] + ((k64 + qb0) ^ bx[j]));
        f.q[1] = *(const unsigned long long*)(Bb + bp0[j] + ((k64 + qb1) ^ bx[j]));
        b[j] = f.v;
      }
#pragma unroll
      for (int i = 0; i < FI; ++i)
#pragma unroll
        for (int j = 0; j < FJ; ++j)
          acc[i][j] = __builtin_amdgcn_mfma_f32_16x16x32_bf16(a[i], b[j], acc[i][j], 0, 0, 0);
    }
  }

#pragma unroll
  for (int i = 0; i < FI; ++i) {
    const int rbase = rowA0 + wr * HM + i * 16 + c4 * 4;
#pragma unroll
    for (int j = 0; j < FJ; ++j) {
      const int col = colB0 + wc * HN + j * 16 + l15;
      if (col < N) {
        float bv = BIAS ? bias[col] : 0.f;
#pragma unroll
        for (int t = 0; t < 4; ++t) {
          float v = acc[i][j][t] + bv;
          if (GELU) {
            float z = 1.5957691216057308f * (v + 0.044715f * v * v * v);
            float th = 1.f - 2.f / (__expf(z) + 1.f);
            v = 0.5f * v * (1.f + th);
          }
          size_t o = (size_t)(rbase + t) * N + col;
          if (RES)          ((float*)outp)[o] = v + res[o];
          else if (OUTBF16) ((ushort_t*)outp)[o] = f2bu(v);
          else              ((float*)outp)[o] = v;
        }
      }
    }
  }
}

// ---------------------------------------------------------------- MFMA flash attention
__global__ __launch_bounds__(256) void fattn_kernel(
    const ushort_t* __restrict__ qkv, ushort_t* __restrict__ y) {
  const int id = blockIdx.x;
  const int w32 = id / NHEAD;
  const int h = id - w32 * NHEAD;
  const int qb = (w32 & 1) ? (w32 >> 1) : (31 - (w32 >> 1));
  const int q0 = qb * 64;

  __shared__ ushort_t Ksm[64 * 64];
  __shared__ ushort_t Vsm[64 * 64];
  __shared__ ushort_t Psm[4 * 16 * 64];

  const int tid = threadIdx.x;
  const int lane = tid & 63, wv = tid >> 6;
  const int l15 = lane & 15, c4 = lane >> 4;
  const int r7 = l15 & 7;

  const ushort_t* qrow = qkv + (size_t)(q0 + wv * 16 + l15) * (3 * DMODEL) + h * DHEAD;
  const short8 qf0 = *(const short8*)(qrow + c4 * 8);
  const short8 qf1 = *(const short8*)(qrow + 32 + c4 * 8);

  const ushort_t* ksrc[2]; ushort_t* kdst[2];
#pragma unroll
  for (int s = 0; s < 2; ++s) {
    int row = wv * 16 + s * 8 + (lane >> 3);
    int cs = (lane & 7) ^ (row & 7);
    ksrc[s] = qkv + (size_t)row * (3 * DMODEL) + DMODEL + h * DHEAD + cs * 8;
    kdst[s] = Ksm + ((wv * 2 + s) * 64) * 8;
  }
  const int vk = tid & 63, vd0 = (tid >> 6) * 8;
  const ushort_t* vsrc = qkv + (size_t)vk * (3 * DMODEL) + 2 * DMODEL + h * DHEAD;
  const int vkoff = ((vk >> 3) << 3) + (vk & 7);

  float m[4] = {-1e30f, -1e30f, -1e30f, -1e30f};
  float l[4] = {};
  f32x4 acc[4] = {};
  ushort_t* Pw = Psm + wv * 1024;

  for (int k0 = 0; k0 <= q0; k0 += 64) {
    const size_t koff = (size_t)k0 * (3 * DMODEL);
    short8 v0 = *(const short8*)(vsrc + koff + vd0);
    short8 v1 = *(const short8*)(vsrc + koff + vd0 + 32);
    __syncthreads();
#pragma unroll
    for (int s = 0; s < 2; ++s) gload_lds16(ksrc[s] + koff, kdst[s]);
#pragma unroll
    for (int j = 0; j < 8; ++j) {
      int d = vd0 + j;
      Vsm[d * 64 + (vkoff ^ ((d & 7) << 3))] = (ushort_t)v0[j];
      int d2 = d + 32;
      Vsm[d2 * 64 + (vkoff ^ ((d2 & 7) << 3))] = (ushort_t)v1[j];
    }
    __syncthreads();

    f32x4 sv[4];
#pragma unroll
    for (int kt = 0; kt < 4; ++kt) {
      const ushort_t* krow = Ksm + (kt * 16 + l15) * 64;
      short8 kb0 = *(const short8*)(krow + ((c4 ^ r7) << 3));
      short8 kb1 = *(const short8*)(krow + (((4 + c4) ^ r7) << 3));
      f32x4 s = {};
      s = __builtin_amdgcn_mfma_f32_16x16x32_bf16(qf0, kb0, s, 0, 0, 0);
      s = __builtin_amdgcn_mfma_f32_16x16x32_bf16(qf1, kb1, s, 0, 0, 0);
      sv[kt] = s * 0.125f;
    }
    if (k0 == q0) {
#pragma unroll
      for (int kt = 0; kt < 4; ++kt)
#pragma unroll
        for (int r = 0; r < 4; ++r)
          if (kt * 16 + l15 > wv * 16 + c4 * 4 + r) sv[kt][r] = -1e30f;
    }

#pragma unroll
    for (int r = 0; r < 4; ++r) {
      float mv = fmaxf(fmaxf(sv[0][r], sv[1][r]), fmaxf(sv[2][r], sv[3][r]));
      mv = fmaxf(mv, __shfl_xor(mv, 1));
      mv = fmaxf(mv, __shfl_xor(mv, 2));
      mv = fmaxf(mv, __shfl_xor(mv, 4));
      mv = fmaxf(mv, __shfl_xor(mv, 8));
      float nm = fmaxf(m[r], mv);
      float sc = __expf(m[r] - nm);
      m[r] = nm;
      const int row = c4 * 4 + r;
      float sum = 0.f;
#pragma unroll
      for (int kt = 0; kt < 4; ++kt) {
        float p = __expf(sv[kt][r] - nm);
        sum += p;
        Pw[row * 64 + (((kt * 2 + (l15 >> 3)) ^ (row & 7)) << 3) + (l15 & 7)] = f2bu(p);
      }
      sum += __shfl_xor(sum, 1);
      sum += __shfl_xor(sum, 2);
      sum += __shfl_xor(sum, 4);
      sum += __shfl_xor(sum, 8);
      l[r] = l[r] * sc + sum;
#pragma unroll
      for (int j = 0; j < 4; ++j) acc[j][r] *= sc;
    }

    const ushort_t* prow = Pw + l15 * 64;
    short8 pa0 = *(const short8*)(prow + ((c4 ^ r7) << 3));
    short8 pa1 = *(const short8*)(prow + (((4 + c4) ^ r7) << 3));
#pragma unroll
    for (int j = 0; j < 4; ++j) {
      const ushort_t* vrow = Vsm + (j * 16 + l15) * 64;
      short8 vb0 = *(const short8*)(vrow + ((c4 ^ r7) << 3));
      short8 vb1 = *(const short8*)(vrow + (((4 + c4) ^ r7) << 3));
      acc[j] = __builtin_amdgcn_mfma_f32_16x16x32_bf16(pa0, vb0, acc[j], 0, 0, 0);
      acc[j] = __builtin_amdgcn_mfma_f32_16x16x32_bf16(pa1, vb1, acc[j], 0, 0, 0);
    }
  }

  float inv[4];
#pragma unroll
  for (int r = 0; r < 4; ++r) inv[r] = 1.f / l[r];
#pragma unroll
  for (int j = 0; j < 4; ++j)
#pragma unroll
    for (int r = 0; r < 4; ++r)
      y[(size_t)(q0 + wv * 16 + c4 * 4 + r) * DMODEL + h * DHEAD + j * 16 + l15] =
          f2bu(acc[j][r] * inv[r]);
}

// ---------------------------------------------------------------- driver
extern "C" void kernel_launch(void* const* d_in, const int* in_sizes, int n_in,
                              void* d_out, int out_size, void* d_ws, size_t ws_size,
                              hipStream_t stream) {
  const int*   tokens = (const int*)d_in[0];
  const float* wte    = (const float*)d_in[1];
  const float* wpe    = (const float*)d_in[2];
  const float* ln1_w  = (const float*)d_in[3];
  const float* ln1_b  = (const float*)d_in[4];
  const float* qkv_w  = (const float*)d_in[5];
  const float* qkv_b  = (const float*)d_in[6];
  const float* proj_w = (const float*)d_in[7];
  const float* proj_b = (const float*)d_in[8];
  const float* ln2_w  = (const float*)d_in[9];
  const float* ln2_b  = (const float*)d_in[10];
  const float* fc_w   = (const float*)d_in[11];
  const float* fc_b   = (const float*)d_in[12];
  const float* fcp_w  = (const float*)d_in[13];
  const float* fcp_b  = (const float*)d_in[14];
  const float* lnf_w  = (const float*)d_in[15];
  const float* lnf_b  = (const float*)d_in[16];
  float* out = (float*)d_out;

  char* p = (char*)d_ws;
  auto alloc = [&](size_t bytes) { char* r = p; p += (bytes + 255) & ~(size_t)255; return r; };
  float*    x     = (float*)alloc((size_t)TSEQ * DMODEL * 4);
  ushort_t* lnb   = (ushort_t*)alloc((size_t)TSEQ * DMODEL * 2);
  ushort_t* buf   = (ushort_t*)alloc((size_t)TSEQ * 4 * DMODEL * 2); // qkv|y == hfc
  ushort_t* wteb  = (ushort_t*)alloc((size_t)VPAD * DMODEL * 2);
  ushort_t* qkvwt = (ushort_t*)alloc((size_t)NLAYER * 3 * DMODEL * DMODEL * 2);
  ushort_t* projwt= (ushort_t*)alloc((size_t)NLAYER * DMODEL * DMODEL * 2);
  ushort_t* fcwt  = (ushort_t*)alloc((size_t)NLAYER * 4 * DMODEL * DMODEL * 2);
  ushort_t* fcpwt = (ushort_t*)alloc((size_t)NLAYER * 4 * DMODEL * DMODEL * 2);
  ushort_t* qkvb  = buf;
  ushort_t* yb    = buf + (size_t)TSEQ * 3 * DMODEL;
  ushort_t* hfcb  = buf;

  dim3 b256(256);

  // zero the vocab padding rows of wteb (read by B-staging, write-guarded)
  hipMemsetAsync(wteb + (size_t)VOCAB * DMODEL, 0,
                 (size_t)(VPAD - VOCAB) * DMODEL * 2, stream);
  cvt_kernel<<<dim3(4096), b256, 0, stream>>>(wte, wteb, VOCAB * DMODEL / 4);
  tcvt_kernel<<<dim3(3 * DMODEL / 32, DMODEL / 32, NLAYER), b256, 0, stream>>>(
      qkv_w, qkvwt, DMODEL, 3 * DMODEL, (long long)3 * DMODEL * DMODEL);
  tcvt_kernel<<<dim3(DMODEL / 32, DMODEL / 32, NLAYER), b256, 0, stream>>>(
      proj_w, projwt, DMODEL, DMODEL, (long long)DMODEL * DMODEL);
  tcvt_kernel<<<dim3(4 * DMODEL / 32, DMODEL / 32, NLAYER), b256, 0, stream>>>(
      fc_w, fcwt, DMODEL, 4 * DMODEL, (long long)4 * DMODEL * DMODEL);
  tcvt_kernel<<<dim3(DMODEL / 32, 4 * DMODEL / 32, NLAYER), b256, 0, stream>>>(
      fcp_w, fcpwt, 4 * DMODEL, DMODEL, (long long)4 * DMODEL * DMODEL);

  embed_kernel<<<dim3(TSEQ * DMODEL / 256), b256, 0, stream>>>(tokens, wte, wpe, x);

  for (int l = 0; l < NLAYER; ++l) {
    ln_kernel<<<dim3(TSEQ), b256, 0, stream>>>(x, ln1_w + l * DMODEL, ln1_b + l * DMODEL, lnb);
    // qkv: 64x128 tile -> 576 blocks (2.25/CU co-residency)
    mm_kernel<64, 128, true, false, false, true, false><<<dim3(32 * 18), b256, 0, stream>>>(
        lnb, qkvwt + (size_t)l * 3 * DMODEL * DMODEL, qkv_b + (size_t)l * 3 * DMODEL,
        nullptr, qkvb, 3 * DMODEL, DMODEL, 32, 576);
    fattn_kernel<<<dim3(32 * NHEAD), b256, 0, stream>>>(qkvb, yb);
    mm_kernel<64, 64, true, true, false, false, false><<<dim3(12 * 32), b256, 0, stream>>>(
        yb, projwt + (size_t)l * DMODEL * DMODEL, proj_b + (size_t)l * DMODEL,
        x, x, DMODEL, DMODEL, 32, 384);
    ln_kernel<<<dim3(TSEQ), b256, 0, stream>>>(x, ln2_w + l * DMODEL, ln2_b + l * DMODEL, lnb);
    // fc: 64x128 tile -> 768 blocks (3/CU)
    mm_kernel<64, 128, true, false, true, true, false><<<dim3(32 * 24), b256, 0, stream>>>(
        lnb, fcwt + (size_t)l * 4 * DMODEL * DMODEL, fc_b + (size_t)l * 4 * DMODEL,
        nullptr, hfcb, 4 * DMODEL, DMODEL, 32, 768);
    mm_kernel<64, 64, true, true, false, false, false><<<dim3(12 * 32), b256, 0, stream>>>(
        hfcb, fcpwt + (size_t)l * DMODEL * 4 * DMODEL, fcp_b + (size_t)l * DMODEL,
        x, x, DMODEL, 4 * DMODEL, 32, 384);
  }

  ln_kernel<<<dim3(TSEQ), b256, 0, stream>>>(x, lnf_w, lnf_b, lnb);
  mm_kernel<128, 128, false, false, false, false, true><<<dim3(393 * 16), b256, 0, stream>>>(
      lnb, wteb, nullptr, nullptr, out, VOCAB, DMODEL, 16, 393 * 16);
}